// Round 2
// baseline (270.768 us; speedup 1.0000x reference)
//
#include <hip/hip_runtime.h>
#include <hip/hip_fp16.h>
#include <cstdint>
#include <cstddef>

// DenseCaps dynamic routing, MI355X.
// B=256 batch, R=2048 routes, NC=10 classes, OUT=16, IN=8, 3 iters.
//
// R1 post-mortem: bf16 u_hat storage fails c-output (absmax 5.5e-2 > 2e-2)
// via the feedback path s->v->t->bB. R2: u_hat stored as fp16 (same 168 MB,
// 8x lower quantization error, predicted c absmax ~7e-3).
//
// Pipeline (all on stream):
//   memset s=0
//   K0:   c0 = softmax(b_in) per route            [R,NC]
//   A:    u_hat(fp16) = x @ W  -> ws              [B,R,NC*OUT] (168 MB)
//   P<0>: s += sum_r c0 * u_hat                   (atomic into s)
//   Bsq:  v = squash(s); s = 0
//   P<1>: t=dot(u,v); bB=b_in+t; c=softmax; s+=c*u
//   Bsq ; P<2> ; Bsq ; P<3> (writes c -> out) ; Bsq(final, v -> out)
//
// bB is aliased onto the c-region of d_out (read-then-write same address
// within the same thread in P<2>/P<3> -> safe).

#define B_   256
#define R_   2048
#define NC_  10
#define OD_  16
#define IN_  8

__device__ __forceinline__ float rsum16(float x){
  x += __shfl_xor(x, 1, 16);
  x += __shfl_xor(x, 2, 16);
  x += __shfl_xor(x, 4, 16);
  x += __shfl_xor(x, 8, 16);
  return x;
}
__device__ __forceinline__ float rmax16(float x){
  x = fmaxf(x, __shfl_xor(x, 1, 16));
  x = fmaxf(x, __shfl_xor(x, 2, 16));
  x = fmaxf(x, __shfl_xor(x, 4, 16));
  x = fmaxf(x, __shfl_xor(x, 8, 16));
  return x;
}
// two fp32 -> packed fp16x2 (RNE)
__device__ __forceinline__ unsigned pack_f16(float a, float b){
  __half2 h = __floats2half2_rn(a, b);
  return *(unsigned*)&h;
}
__device__ __forceinline__ void unpack8(uint4 d, float* f){
  float2 t;
  t = __half22float2(*(__half2*)&d.x); f[0] = t.x; f[1] = t.y;
  t = __half22float2(*(__half2*)&d.y); f[2] = t.x; f[3] = t.y;
  t = __half22float2(*(__half2*)&d.z); f[4] = t.x; f[5] = t.y;
  t = __half22float2(*(__half2*)&d.w); f[6] = t.x; f[7] = t.y;
}

// ---------- K0: c0 = softmax(b_in) over classes, per route ----------
__global__ __launch_bounds__(256) void c0_kernel(const float* __restrict__ b_in,
                                                 float* __restrict__ c0){
  int r = blockIdx.x * 256 + threadIdx.x;
  if (r >= R_) return;
  float t[NC_];
  float m = -1e30f;
  #pragma unroll
  for (int n = 0; n < NC_; ++n){ t[n] = b_in[r * NC_ + n]; m = fmaxf(m, t[n]); }
  float sum = 0.f;
  #pragma unroll
  for (int n = 0; n < NC_; ++n){ t[n] = __expf(t[n] - m); sum += t[n]; }
  float inv = 1.f / sum;
  #pragma unroll
  for (int n = 0; n < NC_; ++n) c0[r * NC_ + n] = t[n] * inv;
}

// ---------- A: u_hat (fp16) producer. One block per route r. ----------
// Thread b computes all 160 outputs for (b, r); W[r] staged in LDS
// (all lanes read the same address -> LDS broadcast, conflict-free).
__global__ __launch_bounds__(256) void uhat_kernel(const float* __restrict__ x,
                                                   const float* __restrict__ W,
                                                   uint32_t* __restrict__ U){
  const int r = blockIdx.x;
  __shared__ float Wl[IN_ * 160];
  {
    const float4* Wg = (const float4*)(W + (size_t)r * (IN_ * 160));
    float4* Wl4 = (float4*)Wl;
    for (int i = threadIdx.x; i < (IN_ * 160) / 4; i += 256) Wl4[i] = Wg[i];
  }
  __syncthreads();
  const int b = threadIdx.x;
  const float4* xp = (const float4*)(x + ((size_t)b * R_ + r) * IN_);
  float4 xa = xp[0], xb = xp[1];
  float xr[8] = {xa.x, xa.y, xa.z, xa.w, xb.x, xb.y, xb.z, xb.w};
  uint32_t* out = U + (((size_t)b * R_ + r) * 160) / 2;   // 80 dwords per (b,r) row
  const float4* Wl4 = (const float4*)Wl;
  #pragma unroll 4
  for (int co = 0; co < 40; ++co){
    float4 u = make_float4(0.f, 0.f, 0.f, 0.f);
    #pragma unroll
    for (int i = 0; i < 8; ++i){
      float4 w = Wl4[i * 40 + co];
      u.x = fmaf(xr[i], w.x, u.x);
      u.y = fmaf(xr[i], w.y, u.y);
      u.z = fmaf(xr[i], w.z, u.z);
      u.w = fmaf(xr[i], w.w, u.w);
    }
    uint2 p; p.x = pack_f16(u.x, u.y); p.y = pack_f16(u.z, u.w);
    ((uint2*)out)[co] = p;
  }
}

// ---------- P<MODE>: fused routing pass ----------
// MODE 0: s += c0 * u_hat (no agreement)
// MODE 1: bold = b_in (broadcast), write bB
// MODE 2: bold = bB, write bB
// MODE 3: bold = bB, write c to out (no bB write)
// Block = (b, r-chunk of 256). Thread = (r_sub in [0,16), n-lane in [0,16), 10 active).
template<int MODE>
__global__ __launch_bounds__(256) void pass_kernel(
    const uint32_t* __restrict__ U,    // u_hat fp16, [B][R][160]
    const float*    __restrict__ c0,   // [R][NC]   (MODE 0)
    const float*    __restrict__ b_in, // [R][NC]   (MODE 1)
    float*          __restrict__ bB,   // [B][R][NC] (alias of out c-region)
    const float*    __restrict__ v,    // [B][NC*OD]
    float*          __restrict__ s)    // [B][NC*OD]
{
  const int b  = blockIdx.x >> 3;
  const int rc = blockIdx.x & 7;
  const int n  = threadIdx.x & 15;
  const int rs = threadIdx.x >> 4;
  const int nn = (n < NC_) ? n : (NC_ - 1);

  float vreg[16];
  if (MODE != 0){
    const float* vp = v + b * 160 + nn * 16;
    #pragma unroll
    for (int o = 0; o < 16; ++o) vreg[o] = vp[o];
  }
  float acc[16];
  #pragma unroll
  for (int o = 0; o < 16; ++o) acc[o] = 0.f;

  const int r0 = rc * 256;
  for (int rr = 0; rr < 16; ++rr){
    const int r = r0 + rr * 16 + rs;
    const size_t row = (size_t)b * R_ + r;
    // 16 fp16 = 32B per thread; group of 16 lanes reads 512B contiguous
    const uint4* up = (const uint4*)(U + row * 80 + n * 8);
    float uf[16];
    unpack8(up[0], uf);
    unpack8(up[1], uf + 8);

    float c;
    if (MODE == 0){
      c = c0[r * NC_ + nn];
      if (n >= NC_) c = 0.f;
    } else {
      float t = 0.f;
      #pragma unroll
      for (int o = 0; o < 16; ++o) t = fmaf(uf[o], vreg[o], t);
      float bold = (MODE == 1) ? b_in[r * NC_ + nn] : bB[row * NC_ + nn];
      float bnew = (n < NC_) ? (bold + t) : -1e30f;
      float m = rmax16(bnew);
      float e = __expf(bnew - m);           // idle lanes -> 0
      float sum = rsum16(e);
      c = e / sum;
      if (MODE == 3){
        if (n < NC_) bB[row * NC_ + n] = c;     // bB aliases out c-region
      } else {
        if (n < NC_) bB[row * NC_ + n] = bnew;
      }
    }
    #pragma unroll
    for (int o = 0; o < 16; ++o) acc[o] = fmaf(c, uf[o], acc[o]);
  }

  // block reduction over the 16 r_sub partials, then atomics into s
  __shared__ float sd[16 * 16 * 17];   // [rs][n][o], padded to 17
  #pragma unroll
  for (int o = 0; o < 16; ++o) sd[rs * 272 + n * 17 + o] = acc[o];
  __syncthreads();
  const int n2 = threadIdx.x >> 4;
  const int o2 = threadIdx.x & 15;
  if (n2 < NC_){
    float tot = 0.f;
    #pragma unroll
    for (int k = 0; k < 16; ++k) tot += sd[k * 272 + n2 * 17 + o2];
    atomicAdd(&s[b * 160 + n2 * 16 + o2], tot);
  }
}

// ---------- Bsq: v = squash(s), optionally zero s ----------
template<bool FINAL>
__global__ __launch_bounds__(256) void squash_kernel(float* __restrict__ s,
                                                     float* __restrict__ vout){
  int g = blockIdx.x * 256 + threadIdx.x;   // 0..40959, 16 lanes per (b,n) row
  float xv = s[g];
  float ss = rsum16(xv * xv);
  float norm = sqrtf(ss);
  float f = norm / (1.f + ss + 1e-8f);
  vout[g] = f * xv;
  if (!FINAL) s[g] = 0.f;
}

extern "C" void kernel_launch(void* const* d_in, const int* in_sizes, int n_in,
                              void* d_out, int out_size, void* d_ws, size_t ws_size,
                              hipStream_t stream){
  const float* x    = (const float*)d_in[0];   // [256,2048,8]
  const float* W    = (const float*)d_in[1];   // [2048,8,160]
  const float* b_in = (const float*)d_in[2];   // [2048,10]
  float* out = (float*)d_out;
  float* out_v = out;                 // 40960 floats
  float* bB    = out + 40960;         // [B][R][NC] — also the c output region

  char* w = (char*)d_ws;
  uint32_t* U = (uint32_t*)w;                                   // 167,772,160 B (fp16 u_hat)
  float* s  = (float*)(w + 167772160);                          // 163,840 B
  float* v  = (float*)(w + 167772160 + 163840);                 // 163,840 B
  float* c0 = (float*)(w + 167772160 + 2 * 163840);             // 81,920 B

  hipMemsetAsync(s, 0, 40960 * sizeof(float), stream);
  c0_kernel<<<8, 256, 0, stream>>>(b_in, c0);
  uhat_kernel<<<R_, 256, 0, stream>>>(x, W, U);

  pass_kernel<0><<<2048, 256, 0, stream>>>(U, c0, b_in, bB, v, s);
  squash_kernel<false><<<160, 256, 0, stream>>>(s, v);
  pass_kernel<1><<<2048, 256, 0, stream>>>(U, c0, b_in, bB, v, s);
  squash_kernel<false><<<160, 256, 0, stream>>>(s, v);
  pass_kernel<2><<<2048, 256, 0, stream>>>(U, c0, b_in, bB, v, s);
  squash_kernel<false><<<160, 256, 0, stream>>>(s, v);
  pass_kernel<3><<<2048, 256, 0, stream>>>(U, c0, b_in, bB, v, s);
  squash_kernel<true><<<160, 256, 0, stream>>>(s, out_v);
}